// Round 1
// baseline (1489.008 us; speedup 1.0000x reference)
//
#include <hip/hip_runtime.h>
#include <hip/hip_bf16.h>

typedef __bf16 bf16;
typedef __bf16 bf16x8 __attribute__((ext_vector_type(8)));
typedef float  f32x4  __attribute__((ext_vector_type(4)));
typedef short  s16x4  __attribute__((ext_vector_type(4)));
typedef short  s16x8  __attribute__((ext_vector_type(8)));

#define B_    2
#define S_    4096
#define DM_   2048
#define H_    16
#define D_    128
#define NSEL_ 64

static __device__ __forceinline__ void gload_lds16(const void* g, void* l) {
  __builtin_amdgcn_global_load_lds((const __attribute__((address_space(1))) void*)g,
                                   (__attribute__((address_space(3))) void*)l, 16, 0, 0);
}

static __device__ __forceinline__ short bfbits(float f) {
  return (short)__builtin_bit_cast(unsigned short, (bf16)f);
}

static __device__ __forceinline__ f32x4 mfma16x16x16bf16(s16x4 a, s16x4 b, f32x4 c) {
#if __has_builtin(__builtin_amdgcn_mfma_f32_16x16x16_bf16_1k)
  return __builtin_amdgcn_mfma_f32_16x16x16_bf16_1k(a, b, c, 0, 0, 0);
#else
  f32x4 d;
  asm volatile("v_mfma_f32_16x16x16_bf16 %0, %1, %2, %3"
               : "=v"(d) : "v"(a), "v"(b), "v"(c));
  return d;
#endif
}

// ---------------- pre-pass: f32 -> bf16 convert (vectorized, G13) -------------
__global__ __launch_bounds__(256) void cvt_x_kernel(const float* __restrict__ in,
                                                    bf16* __restrict__ out) {
  size_t i = (size_t)blockIdx.x * 256 + threadIdx.x;   // one per 8 elems
  const float4* p = (const float4*)in + i * 2;
  float4 a = p[0], b = p[1];
  s16x8 o;
  o[0] = bfbits(a.x); o[1] = bfbits(a.y); o[2] = bfbits(a.z); o[3] = bfbits(a.w);
  o[4] = bfbits(b.x); o[5] = bfbits(b.y); o[6] = bfbits(b.z); o[7] = bfbits(b.w);
  *(s16x8*)(out + i * 8) = o;
}

// ---------------- pre-pass: W [K][N] f32 -> WT [N][K] bf16 --------------------
__global__ __launch_bounds__(256) void transpose_cvt_kernel(const float* __restrict__ W,
                                                            bf16* __restrict__ WT) {
  __shared__ float tile[32][33];
  int tx = threadIdx.x, ty = threadIdx.y;
  int c0 = blockIdx.x * 32, r0 = blockIdx.y * 32;
#pragma unroll
  for (int j = ty; j < 32; j += 8)
    tile[j][tx] = W[(size_t)(r0 + j) * 2048 + c0 + tx];
  __syncthreads();
#pragma unroll
  for (int j = ty; j < 32; j += 8)
    WT[(size_t)(c0 + j) * 2048 + r0 + tx] = (bf16)tile[tx][j];
}

// ---------------- GEMM: C[M][N] = A[M][K] * Bt[N][K]^T  (m97 structure) -------
// LDS layout per operand tile: [g:4][row:128][8 elems] bf16 (8 KiB) — linear for
// global_load_lds, conflict-free for ds_read_b128 fragment reads.
// MODE 0: store bf16 to [B,H,S,D]; MODE 1: store bf16 to [B,H,D,S] (V^T);
// MODE 2: store f32 row-major [M][N].
template <int MODE>
__global__ __launch_bounds__(256) void gemm_bt(const bf16* __restrict__ A,
                                               const bf16* __restrict__ Bt,
                                               void* __restrict__ outp,
                                               int M, int N, int K) {
  __shared__ __align__(16) bf16 ldsA[4096];
  __shared__ __align__(16) bf16 ldsB[4096];
  int nbn = N >> 7;
  int nwg = gridDim.x;
  int bid = blockIdx.x;
  int wg  = (bid & 7) * (nwg >> 3) + (bid >> 3);   // XCD swizzle (nwg % 8 == 0)
  int bm = wg / nbn, bn = wg % nbn;
  int m0 = bm << 7, n0 = bn << 7;
  int tid = threadIdx.x;
  int lane = tid & 63, wid = tid >> 6;
  int wr = wid >> 1, wc = wid & 1;
  int lr = lane & 15, g = lane >> 4;

  f32x4 acc[4][4] = {};

  // staging addressing: call c, idx = c*256 + tid; g = idx>>7, row = idx&127
  int g0 = tid >> 7,           r0 = tid & 127;
  int g1 = (256 + tid) >> 7,   r1 = (256 + tid) & 127;
  const bf16* a0 = A  + (size_t)(m0 + r0) * K + g0 * 8;
  const bf16* a1 = A  + (size_t)(m0 + r1) * K + g1 * 8;
  const bf16* b0 = Bt + (size_t)(n0 + r0) * K + g0 * 8;
  const bf16* b1 = Bt + (size_t)(n0 + r1) * K + g1 * 8;
  bf16* lA0 = ldsA + wid * 512;          // wave-uniform LDS bases; HW adds lane*16
  bf16* lA1 = ldsA + 2048 + wid * 512;
  bf16* lB0 = ldsB + wid * 512;
  bf16* lB1 = ldsB + 2048 + wid * 512;

  for (int k0 = 0; k0 < K; k0 += 32) {
    gload_lds16(a0 + k0, lA0);
    gload_lds16(a1 + k0, lA1);
    gload_lds16(b0 + k0, lB0);
    gload_lds16(b1 + k0, lB1);
    __syncthreads();
    bf16x8 af[4], bfr[4];
#pragma unroll
    for (int m = 0; m < 4; ++m) {
      int row = wr * 64 + m * 16 + lr;
      af[m] = *(const bf16x8*)(ldsA + (g * 128 + row) * 8);
    }
#pragma unroll
    for (int n = 0; n < 4; ++n) {
      int row = wc * 64 + n * 16 + lr;
      bfr[n] = *(const bf16x8*)(ldsB + (g * 128 + row) * 8);
    }
#pragma unroll
    for (int m = 0; m < 4; ++m)
#pragma unroll
      for (int n = 0; n < 4; ++n)
        acc[m][n] = __builtin_amdgcn_mfma_f32_16x16x32_bf16(af[m], bfr[n], acc[m][n], 0, 0, 0);
    __syncthreads();
  }

  // epilogue — C layout: col = lane&15, row = (lane>>4)*4 + r  [m89]
  if constexpr (MODE == 2) {
    float* O = (float*)outp;
#pragma unroll
    for (int m = 0; m < 4; ++m)
#pragma unroll
      for (int n = 0; n < 4; ++n) {
        int row0 = m0 + wr * 64 + m * 16 + g * 4;
        int col  = n0 + wc * 64 + n * 16 + lr;
#pragma unroll
        for (int r = 0; r < 4; ++r)
          O[(size_t)(row0 + r) * N + col] = acc[m][n][r];
      }
  } else if constexpr (MODE == 0) {
    bf16* O = (bf16*)outp;   // [B,H,S,D]
#pragma unroll
    for (int m = 0; m < 4; ++m)
#pragma unroll
      for (int n = 0; n < 4; ++n) {
        int col = n0 + wc * 64 + n * 16 + lr;
        int h = col >> 7, d = col & 127;
#pragma unroll
        for (int r = 0; r < 4; ++r) {
          int row = m0 + wr * 64 + m * 16 + g * 4 + r;
          int b = row >> 12, s = row & 4095;
          O[(((size_t)(b * 16 + h) * 4096 + s) << 7) + d] = (bf16)acc[m][n][r];
        }
      }
  } else {  // MODE 1: V^T [B,H,D,S], pack 4 consecutive s per store
    bf16* O = (bf16*)outp;
#pragma unroll
    for (int m = 0; m < 4; ++m)
#pragma unroll
      for (int n = 0; n < 4; ++n) {
        int col = n0 + wc * 64 + n * 16 + lr;
        int h = col >> 7, d = col & 127;
        int row0 = m0 + wr * 64 + m * 16 + g * 4;
        int b = row0 >> 12, s = row0 & 4095;
        s16x4 pk;
#pragma unroll
        for (int r = 0; r < 4; ++r) pk[r] = bfbits(acc[m][n][r]);
        *(s16x4*)(O + (((size_t)(b * 16 + h) * 128 + d) << 12) + s) = pk;
      }
  }
}

// ---------------- sparse flash attention (wave-independent, no LDS) -----------
// S^T = mfma(K, Q): col = query (lane&15), row = key ((lane>>4)*4+r)
// O^T = mfma(V^T, P^T): col = query, row = d-in-chunk — softmax state stays lane-local.
__global__ __launch_bounds__(256) void attn_fwd(const bf16* __restrict__ qg,
                                                const bf16* __restrict__ kg,
                                                const bf16* __restrict__ vtg,
                                                const int* __restrict__ anchor,
                                                bf16* __restrict__ out) {
  int tid = threadIdx.x;
  int wid = tid >> 6, lane = tid & 63;
  int gw = blockIdx.x * 4 + wid;          // 0..8191
  int qt = gw & 255, bh = gw >> 8;        // bh = b*16 + h
  int q0 = qt * 16;
  int lr = lane & 15, g = lane >> 4;

  const bf16* qrow = qg + ((size_t)bh * S_ + q0 + lr) * D_;
  bf16x8 qf[4];
#pragma unroll
  for (int kk = 0; kk < 4; ++kk)
    qf[kk] = *(const bf16x8*)(qrow + kk * 32 + g * 8);

  const bf16* kbase = kg  + (size_t)bh * S_ * D_;
  const bf16* vbase = vtg + (size_t)bh * D_ * S_;
  const int*  anc   = anchor + bh * NSEL_;

  const float scale = 0.08838834764831845f;  // 1/sqrt(128)
  float m_run = -INFINITY, l_run = 0.f;
  f32x4 accO[8] = {};
  int q_tok = q0 + lr;

  for (int i = 0; i < NSEL_; ++i) {
    int t = (i == NSEL_ - 1) ? (S_ - 1) / 16 : anc[i];

    // QK^T (swapped): S^T accumulate over D
    f32x4 sc = {};
    const bf16* krow = kbase + (size_t)(t * 16 + lr) * D_;
#pragma unroll
    for (int kk = 0; kk < 4; ++kk) {
      bf16x8 kf = *(const bf16x8*)(krow + kk * 32 + g * 8);
      sc = __builtin_amdgcn_mfma_f32_16x16x32_bf16(kf, qf[kk], sc, 0, 0, 0);
    }

    // scale then causal mask (replace with -1e10, like reference jnp.where)
#pragma unroll
    for (int r = 0; r < 4; ++r) {
      int k_tok = t * 16 + g * 4 + r;
      sc[r] = (k_tok > q_tok) ? -1e10f : sc[r] * scale;
    }

    // row (per-query) max over the 16 keys: regs then across the 4 lane-groups
    float mt = fmaxf(fmaxf(sc[0], sc[1]), fmaxf(sc[2], sc[3]));
    mt = fmaxf(mt, __shfl_xor(mt, 16));
    mt = fmaxf(mt, __shfl_xor(mt, 32));

    float m_old = m_run;
    float m_new = fmaxf(m_old, mt);
    float p0 = __expf(sc[0] - m_new), p1 = __expf(sc[1] - m_new);
    float p2 = __expf(sc[2] - m_new), p3 = __expf(sc[3] - m_new);
    float rs = p0 + p1 + p2 + p3;
    rs += __shfl_xor(rs, 16);
    rs += __shfl_xor(rs, 32);

    float alpha = __expf(m_old - m_new);
    if (__any(m_new > m_old)) {          // skip O rescale when max unchanged (T13-lite)
#pragma unroll
      for (int c = 0; c < 8; ++c) accO[c] *= alpha;
    }
    l_run = l_run * alpha + rs;
    m_run = m_new;

    s16x4 pb;
    pb[0] = bfbits(p0); pb[1] = bfbits(p1); pb[2] = bfbits(p2); pb[3] = bfbits(p3);

    // PV: O^T += V^T · P^T  (16x16x16, K = 16 keys)
#pragma unroll
    for (int c = 0; c < 8; ++c) {
      s16x4 vf = *(const s16x4*)(vbase + ((size_t)(c * 16 + lr) << 12) + t * 16 + g * 4);
      accO[c] = mfma16x16x16bf16(vf, pb, accO[c]);
    }
  }

  float inv = 1.0f / l_run;
  int b = bh >> 4, h = bh & 15;
  bf16* orow = out + ((size_t)(b * S_ + q0 + lr)) * DM_ + h * D_;
#pragma unroll
  for (int c = 0; c < 8; ++c) {
    s16x4 pk;
#pragma unroll
    for (int r = 0; r < 4; ++r) pk[r] = bfbits(accO[c][r] * inv);
    *(s16x4*)(orow + c * 16 + g * 4) = pk;
  }
}

// ------------------------------- launch ---------------------------------------
extern "C" void kernel_launch(void* const* d_in, const int* in_sizes, int n_in,
                              void* d_out, int out_size, void* d_ws, size_t ws_size,
                              hipStream_t stream) {
  const float* x  = (const float*)d_in[0];
  const float* Wq = (const float*)d_in[1];
  const float* Wk = (const float*)d_in[2];
  const float* Wv = (const float*)d_in[3];
  const float* Wo = (const float*)d_in[4];
  const int* anchor = (const int*)d_in[5];

  char* ws = (char*)d_ws;
  const size_t MB = 1024ull * 1024ull;
  bf16* xb   = (bf16*)(ws);             // 32 MB  [B*S][DM] bf16
  bf16* wqT  = (bf16*)(ws + 32 * MB);   //  8 MB  [N][K]
  bf16* wkT  = (bf16*)(ws + 40 * MB);
  bf16* wvT  = (bf16*)(ws + 48 * MB);
  bf16* woT  = (bf16*)(ws + 56 * MB);
  bf16* qT   = (bf16*)(ws + 64 * MB);   // 32 MB  [B,H,S,D]
  bf16* kT   = (bf16*)(ws + 96 * MB);   // 32 MB  [B,H,S,D]
  bf16* vT   = (bf16*)(ws + 128 * MB);  // 32 MB  [B,H,D,S]
  bf16* attn = xb;                       // reuse xb after its last read (V GEMM)

  cvt_x_kernel<<<8192, 256, 0, stream>>>(x, xb);
  dim3 tb(32, 8), tg(64, 64);
  transpose_cvt_kernel<<<tg, tb, 0, stream>>>(Wq, wqT);
  transpose_cvt_kernel<<<tg, tb, 0, stream>>>(Wk, wkT);
  transpose_cvt_kernel<<<tg, tb, 0, stream>>>(Wv, wvT);
  transpose_cvt_kernel<<<tg, tb, 0, stream>>>(Wo, woT);

  const int M = B_ * S_, N = DM_, K = DM_;
  const int nblk = (M / 128) * (N / 128);   // 1024, %8==0 for the XCD swizzle
  gemm_bt<0><<<nblk, 256, 0, stream>>>(xb, wqT, qT, M, N, K);
  gemm_bt<0><<<nblk, 256, 0, stream>>>(xb, wkT, kT, M, N, K);
  gemm_bt<1><<<nblk, 256, 0, stream>>>(xb, wvT, vT, M, N, K);

  attn_fwd<<<2048, 256, 0, stream>>>(qT, kT, vT, anchor, attn);

  gemm_bt<2><<<nblk, 256, 0, stream>>>(attn, woT, d_out, M, N, K);
}

// Round 9
// 1155.339 us; speedup vs baseline: 1.2888x; 1.2888x over previous
//
#include <hip/hip_runtime.h>
#include <hip/hip_bf16.h>

typedef __bf16 bf16;
typedef __bf16 bf16x8 __attribute__((ext_vector_type(8)));
typedef float  f32x4  __attribute__((ext_vector_type(4)));
typedef short  s16x4  __attribute__((ext_vector_type(4)));
typedef short  s16x8  __attribute__((ext_vector_type(8)));

#define B_    2
#define S_    4096
#define DM_   2048
#define H_    16
#define D_    128
#define NSEL_ 64

// JOURNAL: r1 (direct-global attn, 16 q/wave) PASSED 1489us (attn 710us,
// latency/request-rate-bound). r2/r3 (LDS staging variants) NaN; r4 (reg-dbuf
// bundle) NaN; r7 (r1 + 32q/wave only) FINITE 0.51 absmax.
// ROOT CAUSE (r8): mfma16x16x16bf16 helper guard misspelled the builtin
// (real name: __builtin_amdgcn_mfma_f32_16x16x16bf16_1k, no '_' before bf16)
// -> every build silently used an inline-asm fallback with unsound constraints
// ("=v" output not tied to C, not early-clobbered -> regalloc-dependent
// corruption; no compiler MFMA hazard management). r1 passed by allocation
// luck; r2/r3/r4/r7 failures were all plausibly THIS, not races.
// r8 delta: fix the helper (correct builtin spelling; safe "+v"-tied asm
// fallback with s_nops). Everything else byte-identical to r7 (32q/wave).
// r8 never ran (GPU acquisition timeout); r9 = identical resubmission.

static __device__ __forceinline__ void gload_lds16(const void* g, void* l) {
  __builtin_amdgcn_global_load_lds((const __attribute__((address_space(1))) void*)g,
                                   (__attribute__((address_space(3))) void*)l, 16, 0, 0);
}

static __device__ __forceinline__ short bfbits(float f) {
  return (short)__builtin_bit_cast(unsigned short, (bf16)f);
}

static __device__ __forceinline__ f32x4 mfma16x16x16bf16(s16x4 a, s16x4 b, f32x4 c) {
#if __has_builtin(__builtin_amdgcn_mfma_f32_16x16x16bf16_1k)
  return __builtin_amdgcn_mfma_f32_16x16x16bf16_1k(a, b, c, 0, 0, 0);
#elif __has_builtin(__builtin_amdgcn_mfma_f32_16x16x16_bf16)
  return __builtin_amdgcn_mfma_f32_16x16x16_bf16(a, b, c, 0, 0, 0);
#else
  // Safe fallback: D tied to C via "+v" (distinct regs from a/b guaranteed:
  // all three are live-in); protective s_nops cover MFMA->VALU read hazard.
  f32x4 d = c;
  asm volatile("v_mfma_f32_16x16x16_bf16 %0, %1, %2, %0\n\t"
               "s_nop 7\n\t"
               "s_nop 3"
               : "+v"(d) : "v"(a), "v"(b));
  return d;
#endif
}

// ---------------- pre-pass: f32 -> bf16 convert (vectorized, G13) -------------
__global__ __launch_bounds__(256) void cvt_x_kernel(const float* __restrict__ in,
                                                    bf16* __restrict__ out) {
  size_t i = (size_t)blockIdx.x * 256 + threadIdx.x;   // one per 8 elems
  const float4* p = (const float4*)in + i * 2;
  float4 a = p[0], b = p[1];
  s16x8 o;
  o[0] = bfbits(a.x); o[1] = bfbits(a.y); o[2] = bfbits(a.z); o[3] = bfbits(a.w);
  o[4] = bfbits(b.x); o[5] = bfbits(b.y); o[6] = bfbits(b.z); o[7] = bfbits(b.w);
  *(s16x8*)(out + i * 8) = o;
}

// ---------------- pre-pass: W [K][N] f32 -> WT [N][K] bf16 --------------------
__global__ __launch_bounds__(256) void transpose_cvt_kernel(const float* __restrict__ W,
                                                            bf16* __restrict__ WT) {
  __shared__ float tile[32][33];
  int tx = threadIdx.x, ty = threadIdx.y;
  int c0 = blockIdx.x * 32, r0 = blockIdx.y * 32;
#pragma unroll
  for (int j = ty; j < 32; j += 8)
    tile[j][tx] = W[(size_t)(r0 + j) * 2048 + c0 + tx];
  __syncthreads();
#pragma unroll
  for (int j = ty; j < 32; j += 8)
    WT[(size_t)(c0 + j) * 2048 + r0 + tx] = (bf16)tile[tx][j];
}

// ---------------- GEMM: C[M][N] = A[M][K] * Bt[N][K]^T  (m97 structure) -------
template <int MODE>
__global__ __launch_bounds__(256) void gemm_bt(const bf16* __restrict__ A,
                                               const bf16* __restrict__ Bt,
                                               void* __restrict__ outp,
                                               int M, int N, int K) {
  __shared__ __align__(16) bf16 ldsA[4096];
  __shared__ __align__(16) bf16 ldsB[4096];
  int nbn = N >> 7;
  int nwg = gridDim.x;
  int bid = blockIdx.x;
  int wg  = (bid & 7) * (nwg >> 3) + (bid >> 3);   // XCD swizzle (nwg % 8 == 0)
  int bm = wg / nbn, bn = wg % nbn;
  int m0 = bm << 7, n0 = bn << 7;
  int tid = threadIdx.x;
  int lane = tid & 63, wid = tid >> 6;
  int wr = wid >> 1, wc = wid & 1;
  int lr = lane & 15, g = lane >> 4;

  f32x4 acc[4][4] = {};

  int g0 = tid >> 7,           r0 = tid & 127;
  int g1 = (256 + tid) >> 7,   r1 = (256 + tid) & 127;
  const bf16* a0 = A  + (size_t)(m0 + r0) * K + g0 * 8;
  const bf16* a1 = A  + (size_t)(m0 + r1) * K + g1 * 8;
  const bf16* b0 = Bt + (size_t)(n0 + r0) * K + g0 * 8;
  const bf16* b1 = Bt + (size_t)(n0 + r1) * K + g1 * 8;
  bf16* lA0 = ldsA + wid * 512;
  bf16* lA1 = ldsA + 2048 + wid * 512;
  bf16* lB0 = ldsB + wid * 512;
  bf16* lB1 = ldsB + 2048 + wid * 512;

  for (int k0 = 0; k0 < K; k0 += 32) {
    gload_lds16(a0 + k0, lA0);
    gload_lds16(a1 + k0, lA1);
    gload_lds16(b0 + k0, lB0);
    gload_lds16(b1 + k0, lB1);
    __syncthreads();
    bf16x8 af[4], bfr[4];
#pragma unroll
    for (int m = 0; m < 4; ++m) {
      int row = wr * 64 + m * 16 + lr;
      af[m] = *(const bf16x8*)(ldsA + (g * 128 + row) * 8);
    }
#pragma unroll
    for (int n = 0; n < 4; ++n) {
      int row = wc * 64 + n * 16 + lr;
      bfr[n] = *(const bf16x8*)(ldsB + (g * 128 + row) * 8);
    }
#pragma unroll
    for (int m = 0; m < 4; ++m)
#pragma unroll
      for (int n = 0; n < 4; ++n)
        acc[m][n] = __builtin_amdgcn_mfma_f32_16x16x32_bf16(af[m], bfr[n], acc[m][n], 0, 0, 0);
    __syncthreads();
  }

  if constexpr (MODE == 2) {
    float* O = (float*)outp;
#pragma unroll
    for (int m = 0; m < 4; ++m)
#pragma unroll
      for (int n = 0; n < 4; ++n) {
        int row0 = m0 + wr * 64 + m * 16 + g * 4;
        int col  = n0 + wc * 64 + n * 16 + lr;
#pragma unroll
        for (int r = 0; r < 4; ++r)
          O[(size_t)(row0 + r) * N + col] = acc[m][n][r];
      }
  } else if constexpr (MODE == 0) {
    bf16* O = (bf16*)outp;   // [B,H,S,D]
#pragma unroll
    for (int m = 0; m < 4; ++m)
#pragma unroll
      for (int n = 0; n < 4; ++n) {
        int col = n0 + wc * 64 + n * 16 + lr;
        int h = col >> 7, d = col & 127;
#pragma unroll
        for (int r = 0; r < 4; ++r) {
          int row = m0 + wr * 64 + m * 16 + g * 4 + r;
          int b = row >> 12, s = row & 4095;
          O[(((size_t)(b * 16 + h) * 4096 + s) << 7) + d] = (bf16)acc[m][n][r];
        }
      }
  } else {  // MODE 1: V^T [B,H,D,S]
    bf16* O = (bf16*)outp;
#pragma unroll
    for (int m = 0; m < 4; ++m)
#pragma unroll
      for (int n = 0; n < 4; ++n) {
        int col = n0 + wc * 64 + n * 16 + lr;
        int h = col >> 7, d = col & 127;
        int row0 = m0 + wr * 64 + m * 16 + g * 4;
        int b = row0 >> 12, s = row0 & 4095;
        s16x4 pk;
#pragma unroll
        for (int r = 0; r < 4; ++r) pk[r] = bfbits(acc[m][n][r]);
        *(s16x4*)(O + (((size_t)(b * 16 + h) * 128 + d) << 12) + s) = pk;
      }
  }
}

// ---------------- sparse flash attention (r1 dataflow, 32 queries/wave) -------
// Direct global K/V loads, no LDS, no barriers (r1-proven). Each wave handles
// two 16-query groups that SHARE every K and V fragment fetch.
// S^T = mfma(K, Q): col = query (lane&15), row = key ((lane>>4)*4+r)
// O^T = mfma(V^T, P^T): col = query, row = d-in-chunk — softmax state lane-local.
__global__ __launch_bounds__(256) void attn_fwd(const bf16* __restrict__ qg,
                                                const bf16* __restrict__ kg,
                                                const bf16* __restrict__ vtg,
                                                const int* __restrict__ anchor,
                                                bf16* __restrict__ out) {
  int tid = threadIdx.x;
  int wid = tid >> 6, lane = tid & 63;
  int gw = blockIdx.x * 4 + wid;          // 0..4095
  int qt = gw & 127, bh = gw >> 7;        // bh = b*16 + h
  int q0 = qt * 32;                       // 32 queries per wave (two groups of 16)
  int lr = lane & 15, g = lane >> 4;

  // Q fragments for both query groups (once)
  const bf16* qrow = qg + ((size_t)bh * S_ + q0 + lr) * D_;
  bf16x8 qf1[4], qf2[4];
#pragma unroll
  for (int kk = 0; kk < 4; ++kk) {
    qf1[kk] = *(const bf16x8*)(qrow + kk * 32 + g * 8);
    qf2[kk] = *(const bf16x8*)(qrow + 16 * D_ + kk * 32 + g * 8);
  }

  const bf16* kbase = kg  + (size_t)bh * S_ * D_;
  const bf16* vbase = vtg + (size_t)bh * D_ * S_;
  const int*  anc   = anchor + bh * NSEL_;

  const float scale = 0.08838834764831845f;  // 1/sqrt(128)
  float m1 = -INFINITY, l1 = 0.f;
  float m2 = -INFINITY, l2 = 0.f;
  f32x4 acc1[8] = {}, acc2[8] = {};
  int q_tok1 = q0 + lr, q_tok2 = q0 + 16 + lr;

  for (int i = 0; i < NSEL_; ++i) {
    int t = (i == NSEL_ - 1) ? (S_ - 1) / 16 : anc[i];

    // QK^T (swapped): S^T accumulate over D; K fragments shared by both groups
    f32x4 sc1 = {}, sc2 = {};
    const bf16* krow = kbase + (size_t)(t * 16 + lr) * D_;
#pragma unroll
    for (int kk = 0; kk < 4; ++kk) {
      bf16x8 kf = *(const bf16x8*)(krow + kk * 32 + g * 8);
      sc1 = __builtin_amdgcn_mfma_f32_16x16x32_bf16(kf, qf1[kk], sc1, 0, 0, 0);
      sc2 = __builtin_amdgcn_mfma_f32_16x16x32_bf16(kf, qf2[kk], sc2, 0, 0, 0);
    }

    // scale then causal mask (replace with -1e10, like reference jnp.where)
#pragma unroll
    for (int r = 0; r < 4; ++r) {
      int k_tok = t * 16 + g * 4 + r;
      sc1[r] = (k_tok > q_tok1) ? -1e10f : sc1[r] * scale;
      sc2[r] = (k_tok > q_tok2) ? -1e10f : sc2[r] * scale;
    }

    // per-query max over the 16 keys: regs then across the 4 lane-groups
    float mt1 = fmaxf(fmaxf(sc1[0], sc1[1]), fmaxf(sc1[2], sc1[3]));
    mt1 = fmaxf(mt1, __shfl_xor(mt1, 16));
    mt1 = fmaxf(mt1, __shfl_xor(mt1, 32));
    float mt2 = fmaxf(fmaxf(sc2[0], sc2[1]), fmaxf(sc2[2], sc2[3]));
    mt2 = fmaxf(mt2, __shfl_xor(mt2, 16));
    mt2 = fmaxf(mt2, __shfl_xor(mt2, 32));

    float mo1 = m1, mn1 = fmaxf(mo1, mt1);
    float mo2 = m2, mn2 = fmaxf(mo2, mt2);

    float p10 = __expf(sc1[0] - mn1), p11 = __expf(sc1[1] - mn1);
    float p12 = __expf(sc1[2] - mn1), p13 = __expf(sc1[3] - mn1);
    float rs1 = p10 + p11 + p12 + p13;
    rs1 += __shfl_xor(rs1, 16);
    rs1 += __shfl_xor(rs1, 32);

    float p20 = __expf(sc2[0] - mn2), p21 = __expf(sc2[1] - mn2);
    float p22 = __expf(sc2[2] - mn2), p23 = __expf(sc2[3] - mn2);
    float rs2 = p20 + p21 + p22 + p23;
    rs2 += __shfl_xor(rs2, 16);
    rs2 += __shfl_xor(rs2, 32);

    float a1 = __expf(mo1 - mn1);
    float a2 = __expf(mo2 - mn2);
    if (__any(mn1 > mo1)) {            // skip O rescale when max unchanged
#pragma unroll
      for (int c = 0; c < 8; ++c) acc1[c] *= a1;
    }
    if (__any(mn2 > mo2)) {
#pragma unroll
      for (int c = 0; c < 8; ++c) acc2[c] *= a2;
    }
    l1 = l1 * a1 + rs1;  m1 = mn1;
    l2 = l2 * a2 + rs2;  m2 = mn2;

    s16x4 pb1, pb2;
    pb1[0] = bfbits(p10); pb1[1] = bfbits(p11); pb1[2] = bfbits(p12); pb1[3] = bfbits(p13);
    pb2[0] = bfbits(p20); pb2[1] = bfbits(p21); pb2[2] = bfbits(p22); pb2[3] = bfbits(p23);

    // PV: O^T += V^T · P^T (16x16x16); V fragments shared by both groups
#pragma unroll
    for (int c = 0; c < 8; ++c) {
      s16x4 vf = *(const s16x4*)(vbase + ((size_t)(c * 16 + lr) << 12) + t * 16 + g * 4);
      acc1[c] = mfma16x16x16bf16(vf, pb1, acc1[c]);
      acc2[c] = mfma16x16x16bf16(vf, pb2, acc2[c]);
    }
  }

  float inv1 = 1.0f / l1, inv2 = 1.0f / l2;
  int b = bh >> 4, h = bh & 15;
  bf16* orow1 = out + ((size_t)(b * S_ + q0 + lr)) * DM_ + h * D_;
  bf16* orow2 = orow1 + (size_t)16 * DM_;
#pragma unroll
  for (int c = 0; c < 8; ++c) {
    s16x4 pk1, pk2;
#pragma unroll
    for (int r = 0; r < 4; ++r) {
      pk1[r] = bfbits(acc1[c][r] * inv1);
      pk2[r] = bfbits(acc2[c][r] * inv2);
    }
    *(s16x4*)(orow1 + c * 16 + g * 4) = pk1;
    *(s16x4*)(orow2 + c * 16 + g * 4) = pk2;
  }
}

// ------------------------------- launch ---------------------------------------
extern "C" void kernel_launch(void* const* d_in, const int* in_sizes, int n_in,
                              void* d_out, int out_size, void* d_ws, size_t ws_size,
                              hipStream_t stream) {
  const float* x  = (const float*)d_in[0];
  const float* Wq = (const float*)d_in[1];
  const float* Wk = (const float*)d_in[2];
  const float* Wv = (const float*)d_in[3];
  const float* Wo = (const float*)d_in[4];
  const int* anchor = (const int*)d_in[5];

  char* ws = (char*)d_ws;
  const size_t MB = 1024ull * 1024ull;
  bf16* xb   = (bf16*)(ws);             // 32 MB  [B*S][DM] bf16
  bf16* wqT  = (bf16*)(ws + 32 * MB);   //  8 MB  [N][K]
  bf16* wkT  = (bf16*)(ws + 40 * MB);
  bf16* wvT  = (bf16*)(ws + 48 * MB);
  bf16* woT  = (bf16*)(ws + 56 * MB);
  bf16* qT   = (bf16*)(ws + 64 * MB);   // 32 MB  [B,H,S,D]
  bf16* kT   = (bf16*)(ws + 96 * MB);   // 32 MB  [B,H,S,D]
  bf16* vT   = (bf16*)(ws + 128 * MB);  // 32 MB  [B,H,D,S]
  bf16* attn = xb;                       // reuse xb after its last read (V GEMM)

  cvt_x_kernel<<<8192, 256, 0, stream>>>(x, xb);
  dim3 tb(32, 8), tg(64, 64);
  transpose_cvt_kernel<<<tg, tb, 0, stream>>>(Wq, wqT);
  transpose_cvt_kernel<<<tg, tb, 0, stream>>>(Wk, wkT);
  transpose_cvt_kernel<<<tg, tb, 0, stream>>>(Wv, wvT);
  transpose_cvt_kernel<<<tg, tb, 0, stream>>>(Wo, woT);

  const int M = B_ * S_, N = DM_, K = DM_;
  const int nblk = (M / 128) * (N / 128);   // 1024, %8==0 for the XCD swizzle
  gemm_bt<0><<<nblk, 256, 0, stream>>>(xb, wqT, qT, M, N, K);
  gemm_bt<0><<<nblk, 256, 0, stream>>>(xb, wkT, kT, M, N, K);
  gemm_bt<1><<<nblk, 256, 0, stream>>>(xb, wvT, vT, M, N, K);

  attn_fwd<<<1024, 256, 0, stream>>>(qT, kT, vT, anchor, attn);

  gemm_bt<2><<<nblk, 256, 0, stream>>>(attn, woT, d_out, M, N, K);
}